// Round 9
// baseline (366.298 us; speedup 1.0000x reference)
//
#include <hip/hip_runtime.h>
#include <hip/hip_fp16.h>
#include <math.h>

// ---------------------------------------------------------------------------
// GCN autoencoder: 4 layers (12->16->8->16->12), N=200K nodes, E=5M edges.
//
// Round 24 (on R23's 358.8 us): gather-focused micro-restructure.
//  * 12-wide tables split into TWO arrays: A = 8 feats (16B rows, dwordx4)
//    + B = 4 feats (8B rows, dwordx2). One visit, two requests (unchanged),
//    but no 32B-pad waste: chunk working set 3.2 -> 2.4 MB, every fetched
//    L2 line 100% useful. Applied to T1 (csr tail) and T4 (t4 epilogue,
//    lane0->A / lane1->B falls out of the existing shfl split).
//  * In-flight quads: UN 3->4 for the 8-wide gathers (latency-bound,
//    1 req/visit), 2->3 for the 12-wide (old 60-VGPR cap was conservative).
// Build phase + partials structure unchanged from R23.
// ---------------------------------------------------------------------------

#define NPB 512                // nodes per bucket; bucket id = dst >> 9
#define MAX_NB 512             // supports N <= 262144
#define CAP 13504              // bucket region capacity (mean 12800 + ~6s)
#define BIN_CHUNK 8192         // edges per workgroup in bin_kernel
#define BIN_TH 512             // threads per workgroup in bin_kernel
#define EPT (BIN_CHUNK / BIN_TH)  // edges per thread (16)
#define MAXB CAP               // LDS col staging capacity (full bucket)

__global__ void init_cur_kernel(int* __restrict__ bucket_cur, int NB) {
    int t = blockIdx.x * blockDim.x + threadIdx.x;
    if (t < NB) bucket_cur[t] = t * CAP;
}

// Block-level LDS counting sort of an 8192-edge chunk (512 threads).
__global__ __launch_bounds__(BIN_TH) void bin_kernel(const int* __restrict__ src,
                                                     const int* __restrict__ dst,
                                                     int* __restrict__ bucket_cur,
                                                     unsigned int* __restrict__ binned,
                                                     int E, int NB) {
    __shared__ int h[MAX_NB];          // hist, then reused as scatter cursor
    __shared__ int scl[MAX_NB + 1];    // block-local exclusive offsets
    __shared__ int base[MAX_NB];       // global run bases
    __shared__ int sscan[BIN_TH];
    __shared__ unsigned int stage[BIN_CHUNK];       // 32 KB
    __shared__ unsigned short bkt16[BIN_CHUNK];     // 16 KB bucket ids
    int cbeg = blockIdx.x * BIN_CHUNK;
    int cend = min(cbeg + BIN_CHUNK, E);
    int chunk_n = cend - cbeg;
    int tid = threadIdx.x;

    for (int t = tid; t < NB; t += BIN_TH) h[t] = 0;
    __syncthreads();
    int myd[EPT];
#pragma unroll
    for (int j = 0; j < EPT; j++) {
        int e = cbeg + tid + j * BIN_TH;
        if (e < cend) {
            myd[j] = dst[e];
            atomicAdd(&h[myd[j] >> 9], 1);
        }
    }
    __syncthreads();
    int v = (tid < NB) ? h[tid] : 0;
    sscan[tid] = v;
    __syncthreads();
    for (int off = 1; off < BIN_TH; off <<= 1) {
        int t = (tid >= off) ? sscan[tid - off] : 0;
        __syncthreads();
        sscan[tid] += t;
        __syncthreads();
    }
    if (tid < NB) {
        scl[tid] = sscan[tid] - v;
        base[tid] = v ? atomicAdd(&bucket_cur[tid], v) : 0;
    }
    if (tid == 0) scl[NB] = chunk_n;
    __syncthreads();
    for (int t = tid; t < NB; t += BIN_TH) h[t] = 0;  // reuse as cursor
    __syncthreads();
#pragma unroll
    for (int j = 0; j < EPT; j++) {
        int e = cbeg + tid + j * BIN_TH;
        if (e < cend) {
            int d = myd[j];
            int bkt = d >> 9;
            int pos = scl[bkt] + atomicAdd(&h[bkt], 1);
            stage[pos] = ((unsigned)src[e] << 9) | (unsigned)(d & 511);
            bkt16[pos] = (unsigned short)bkt;
        }
    }
    __syncthreads();
    for (int k = tid; k < chunk_n; k += BIN_TH) {
        int bkt = bkt16[k];
        binned[base[bkt] + (k - scl[bkt])] = stage[k];
    }
}

// One WG per bucket (512 nodes, 512 threads, ~63 KB LDS -> 2 WGs/CU):
// per-node count + scan, rows/mids/dis emit, 2-way src-half partitioned
// scatter into LDS colbuf, coalesced flush.
// FUSED T1 tail: T1 = x*dis split as A (8 feats, 16B rows) + B (4, 8B).
__global__ __launch_bounds__(512) void csr_bucket_t1_kernel(
    const unsigned int* __restrict__ binned,
    const int* __restrict__ bucket_cur,
    int2* __restrict__ rows, int* __restrict__ mids, float* __restrict__ dis,
    int* __restrict__ col,
    const float* __restrict__ x,
    __half* __restrict__ xlsA, __half* __restrict__ xlsB, int N, int halfN) {
    __shared__ int cnt[NPB];
    __shared__ int cnt0[NPB];
    __shared__ int curA[NPB];
    __shared__ int curB[NPB];
    __shared__ int colbuf[MAXB];   // 54 KB (total ~62.7 KB LDS)
    int b = blockIdx.x;
    int nbase = b << 9;
    int nlocal = min(NPB, N - nbase);
    int beg = b * CAP;
    int bsize = bucket_cur[b] - beg;
    int tid = threadIdx.x;

    cnt[tid] = 0;
    cnt0[tid] = 0;
    __syncthreads();
    for (int k = tid; k < bsize; k += 512) {
        unsigned rec = binned[beg + k];
        int l = rec & 511u;
        int s = (int)(rec >> 9);
        atomicAdd(&cnt[l], 1);
        if (s < halfN) atomicAdd(&cnt0[l], 1);
    }
    __syncthreads();
    int v = cnt[tid];
    int v0 = cnt0[tid];
    curA[tid] = v;
    __syncthreads();
    for (int off = 1; off < 512; off <<= 1) {
        int t = (tid >= off) ? curA[tid - off] : 0;
        __syncthreads();
        curA[tid] += t;
        __syncthreads();
    }
    int excl = curA[tid] - v;
    float d = 1.0f / sqrtf((float)(v + 1));  // +1 self-loop
    if (tid < nlocal) {
        rows[nbase + tid] = make_int2(beg + excl, beg + excl + v);
        mids[nbase + tid] = beg + excl + v0;
        dis[nbase + tid] = d;
    }
    __syncthreads();
    curA[tid] = excl;          // cursor for src < halfN
    curB[tid] = excl + v0;     // cursor for src >= halfN
    __syncthreads();
    if (bsize <= MAXB) {
        for (int k = tid; k < bsize; k += 512) {
            unsigned rec = binned[beg + k];
            int l = rec & 511u;
            int s = (int)(rec >> 9);
            int pos = (s < halfN) ? atomicAdd(&curA[l], 1)
                                  : atomicAdd(&curB[l], 1);
            colbuf[pos] = s;
        }
        __syncthreads();
        for (int k = tid; k < bsize; k += 512) col[beg + k] = colbuf[k];
    } else {  // cannot trigger with CAP sizing; correctness fallback
        for (int k = tid; k < bsize; k += 512) {
            unsigned rec = binned[beg + k];
            int l = rec & 511u;
            int s = (int)(rec >> 9);
            int pos = (s < halfN) ? atomicAdd(&curA[l], 1)
                                  : atomicAdd(&curB[l], 1);
            col[beg + pos] = s;
        }
    }
    // ---- fused T1 = x * dis, split A(8)/B(4) fp16 tables ----------------
    if (tid < nlocal) {
        int i = nbase + tid;
        float h[12];
#pragma unroll
        for (int k = 0; k < 12; k++) h[k] = x[(size_t)i * 12 + k];
        __half2* x2a = (__half2*)xlsA;
        __half2* x2b = (__half2*)xlsB;
#pragma unroll
        for (int k = 0; k < 4; k++) {
            x2a[(size_t)i * 4 + k] =
                __floats2half2_rn(h[2 * k] * d, h[2 * k + 1] * d);
        }
#pragma unroll
        for (int k = 0; k < 2; k++) {
            x2b[(size_t)i * 2 + k] =
                __floats2half2_rn(h[8 + 2 * k] * d, h[9 + 2 * k] * d);
        }
    }
}

// ---------- 8-wide gather core (single table, 16B rows) -------------------
template <int P, int S>
__device__ __forceinline__ void acc_node(const __half2* __restrict__ x2, int c,
                                         float2 (&acc)[P]) {
    __half2 t[P];
#pragma unroll
    for (int k = 0; k < P; k++) t[k] = x2[(size_t)c * S + k];
#pragma unroll
    for (int k = 0; k < P; k++) {
        float2 v = __half22float2(t[k]);
        acc[k].x += v.x;
        acc[k].y += v.y;
    }
}

template <int P, int S>
__device__ __forceinline__ void acc_quad(const __half2* __restrict__ x2, int4 c,
                                         float2 (&acc)[P]) {
    __half2 t[4][P];
#pragma unroll
    for (int k = 0; k < P; k++) t[0][k] = x2[(size_t)c.x * S + k];
#pragma unroll
    for (int k = 0; k < P; k++) t[1][k] = x2[(size_t)c.y * S + k];
#pragma unroll
    for (int k = 0; k < P; k++) t[2][k] = x2[(size_t)c.z * S + k];
#pragma unroll
    for (int k = 0; k < P; k++) t[3][k] = x2[(size_t)c.w * S + k];
#pragma unroll
    for (int k = 0; k < P; k++) {
        float2 a0 = __half22float2(t[0][k]), a1 = __half22float2(t[1][k]);
        float2 a2 = __half22float2(t[2][k]), a3 = __half22float2(t[3][k]);
        acc[k].x += (a0.x + a1.x) + (a2.x + a3.x);
        acc[k].y += (a0.y + a1.y) + (a2.y + a3.y);
    }
}

// Lane-pair gather over [beg,end): UN int4 col quads in flight per lane.
template <int C, int S, int UN>
__device__ __forceinline__ void gather_acc_rng(
    int i, int p, int beg, int end, bool self,
    const int* __restrict__ col, const __half2* __restrict__ x2,
    float2 (&acc)[C / 2]) {
    constexpr int P = C / 2;
#pragma unroll
    for (int k = 0; k < P; k++) {
        if (self && p == 0) acc[k] = __half22float2(x2[(size_t)i * S + k]);
        else acc[k] = make_float2(0.0f, 0.0f);
    }
    int nedge = end - beg;
    int pre = (4 - (beg & 3)) & 3;
    if (pre > nedge) pre = nedge;
    for (int j = p; j < pre; j += 2) acc_node<P, S>(x2, col[beg + j], acc);
    int abeg = beg + pre;
    int nq = (end - abeg) >> 2;  // full aligned quads
    int q = p;
    for (; q + 2 * (UN - 1) < nq; q += 2 * UN) {
        int4 cs[UN];
#pragma unroll
        for (int u = 0; u < UN; u++)
            cs[u] = *reinterpret_cast<const int4*>(col + abeg + 4 * (q + 2 * u));
#pragma unroll
        for (int u = 0; u < UN; u++) acc_quad<P, S>(x2, cs[u], acc);
    }
    for (; q < nq; q += 2) {
        int4 ca = *reinterpret_cast<const int4*>(col + abeg + 4 * q);
        acc_quad<P, S>(x2, ca, acc);
    }
    int tbeg = abeg + 4 * nq;
    for (int j = tbeg + p; j < end; j += 2) acc_node<P, S>(x2, col[j], acc);
#pragma unroll
    for (int k = 0; k < P; k++) {
        acc[k].x += __shfl_xor(acc[k].x, 1);
        acc[k].y += __shfl_xor(acc[k].y, 1);
    }
}

// ---------- 12-wide gather core (split A/B tables, 16B + 8B rows) ---------
__device__ __forceinline__ void acc_node12(const __half2* __restrict__ xA,
                                           const __half2* __restrict__ xB,
                                           int c, float2 (&acc)[6]) {
    __half2 a[4], b[2];
#pragma unroll
    for (int k = 0; k < 4; k++) a[k] = xA[(size_t)c * 4 + k];
#pragma unroll
    for (int k = 0; k < 2; k++) b[k] = xB[(size_t)c * 2 + k];
#pragma unroll
    for (int k = 0; k < 4; k++) {
        float2 v = __half22float2(a[k]);
        acc[k].x += v.x; acc[k].y += v.y;
    }
#pragma unroll
    for (int k = 0; k < 2; k++) {
        float2 v = __half22float2(b[k]);
        acc[4 + k].x += v.x; acc[4 + k].y += v.y;
    }
}

__device__ __forceinline__ void acc_quad12(const __half2* __restrict__ xA,
                                           const __half2* __restrict__ xB,
                                           int4 c, float2 (&acc)[6]) {
    __half2 ta[4][4], tb[4][2];
    int idx[4] = {c.x, c.y, c.z, c.w};
#pragma unroll
    for (int n = 0; n < 4; n++) {
#pragma unroll
        for (int k = 0; k < 4; k++) ta[n][k] = xA[(size_t)idx[n] * 4 + k];
#pragma unroll
        for (int k = 0; k < 2; k++) tb[n][k] = xB[(size_t)idx[n] * 2 + k];
    }
#pragma unroll
    for (int k = 0; k < 4; k++) {
        float2 a0 = __half22float2(ta[0][k]), a1 = __half22float2(ta[1][k]);
        float2 a2 = __half22float2(ta[2][k]), a3 = __half22float2(ta[3][k]);
        acc[k].x += (a0.x + a1.x) + (a2.x + a3.x);
        acc[k].y += (a0.y + a1.y) + (a2.y + a3.y);
    }
#pragma unroll
    for (int k = 0; k < 2; k++) {
        float2 a0 = __half22float2(tb[0][k]), a1 = __half22float2(tb[1][k]);
        float2 a2 = __half22float2(tb[2][k]), a3 = __half22float2(tb[3][k]);
        acc[4 + k].x += (a0.x + a1.x) + (a2.x + a3.x);
        acc[4 + k].y += (a0.y + a1.y) + (a2.y + a3.y);
    }
}

// UN=3 quads in flight per lane (12 visits, 24 requests outstanding).
__device__ __forceinline__ void gather_acc12_rng(
    int i, int p, int beg, int end, bool self,
    const int* __restrict__ col, const __half2* __restrict__ xA,
    const __half2* __restrict__ xB, float2 (&acc)[6]) {
    constexpr int UN = 3;
#pragma unroll
    for (int k = 0; k < 6; k++) acc[k] = make_float2(0.0f, 0.0f);
    if (self && p == 0) {
#pragma unroll
        for (int k = 0; k < 4; k++) acc[k] = __half22float2(xA[(size_t)i * 4 + k]);
#pragma unroll
        for (int k = 0; k < 2; k++) acc[4 + k] = __half22float2(xB[(size_t)i * 2 + k]);
    }
    int nedge = end - beg;
    int pre = (4 - (beg & 3)) & 3;
    if (pre > nedge) pre = nedge;
    for (int j = p; j < pre; j += 2) acc_node12(xA, xB, col[beg + j], acc);
    int abeg = beg + pre;
    int nq = (end - abeg) >> 2;
    int q = p;
    for (; q + 2 * (UN - 1) < nq; q += 2 * UN) {
        int4 cs[UN];
#pragma unroll
        for (int u = 0; u < UN; u++)
            cs[u] = *reinterpret_cast<const int4*>(col + abeg + 4 * (q + 2 * u));
#pragma unroll
        for (int u = 0; u < UN; u++) acc_quad12(xA, xB, cs[u], acc);
    }
    for (; q < nq; q += 2) {
        int4 ca = *reinterpret_cast<const int4*>(col + abeg + 4 * q);
        acc_quad12(xA, xB, ca, acc);
    }
    int tbeg = abeg + 4 * nq;
    for (int j = tbeg + p; j < end; j += 2) acc_node12(xA, xB, col[j], acc);
#pragma unroll
    for (int k = 0; k < 6; k++) {
        acc[k].x += __shfl_xor(acc[k].x, 1);
        acc[k].y += __shfl_xor(acc[k].y, 1);
    }
}

// 12-wide single-visit gather, src-half partitioned. chunk = (blockIdx&7)>=4
// (XCD-affine): chunk c walks sublist c against table half c (2.4 MB slice).
__global__ __launch_bounds__(256) void gather12h_kernel(
    const int2* __restrict__ rows, const int* __restrict__ mids,
    const int* __restrict__ col, const __half* __restrict__ xinA,
    const __half* __restrict__ xinB,
    float* __restrict__ part0, float* __restrict__ part1, int N, int halfN) {
    int grp = blockIdx.x >> 3;
    int sub = blockIdx.x & 7;
    int chunk = sub >> 2;
    int range = (grp << 2) + (sub & 3);
    int t2 = range * 256 + (int)threadIdx.x;
    int i = t2 >> 1;
    int p = t2 & 1;
    if (i >= N) return;
    int2 r = rows[i];
    int m = mids[i];
    int beg = chunk ? m : r.x;
    int end = chunk ? r.y : m;
    bool self = chunk ? (i >= halfN) : (i < halfN);
    float2 acc[6];
    gather_acc12_rng(i, p, beg, end, self, col,
                     (const __half2*)xinA, (const __half2*)xinB, acc);
    float* part = chunk ? part1 : part0;
    float2* ap = (float2*)(part + (size_t)i * 12);
#pragma unroll
    for (int k = 0; k < 6; k++) {
        if ((k & 1) == p) ap[k] = acc[k];
    }
}

// Layer-1 tail: A1 = (part0+part1)*d -> relu(A1@W1+b1) -> @W2 -> *dis
// -> T2 table (8-wide fp16, 16B rows).
__global__ __launch_bounds__(256) void transform12_kernel(
    const float* __restrict__ p0, const float* __restrict__ p1,
    const float* __restrict__ b1, const float* __restrict__ W1,
    const float* __restrict__ W2, const float* __restrict__ dis,
    __half* __restrict__ xout, int N) {
    __shared__ float sW1[12 * 16];
    __shared__ float sW2[16 * 8];
    __shared__ float sB[16];
    if (threadIdx.x < 192) sW1[threadIdx.x] = W1[threadIdx.x];
    if (threadIdx.x < 128) sW2[threadIdx.x] = W2[threadIdx.x];
    if (threadIdx.x < 16) sB[threadIdx.x] = b1[threadIdx.x];
    __syncthreads();
    int i = blockIdx.x * blockDim.x + threadIdx.x;
    if (i >= N) return;
    float d = dis[i];
    float A[12];
    const float4* a4 = (const float4*)(p0 + (size_t)i * 12);
    const float4* b4 = (const float4*)(p1 + (size_t)i * 12);
#pragma unroll
    for (int q = 0; q < 3; q++) {
        float4 va = a4[q], vb = b4[q];
        A[4 * q + 0] = (va.x + vb.x) * d;
        A[4 * q + 1] = (va.y + vb.y) * d;
        A[4 * q + 2] = (va.z + vb.z) * d;
        A[4 * q + 3] = (va.w + vb.w) * d;
    }
    float h[16];
#pragma unroll
    for (int f = 0; f < 16; f++) {
        float acc = sB[f];
#pragma unroll
        for (int k = 0; k < 12; k++) acc = fmaf(A[k], sW1[k * 16 + f], acc);
        h[f] = fmaxf(acc, 0.0f);
    }
    __half2* x2 = (__half2*)xout;
#pragma unroll
    for (int k2 = 0; k2 < 4; k2++) {
        float o0 = 0.0f, o1 = 0.0f;
#pragma unroll
        for (int k = 0; k < 16; k++) {
            o0 = fmaf(h[k], sW2[k * 8 + 2 * k2], o0);
            o1 = fmaf(h[k], sW2[k * 8 + 2 * k2 + 1], o1);
        }
        x2[(size_t)i * 4 + k2] = __floats2half2_rn(o0 * d, o1 * d);
    }
}

// Layer-2 gather (8-wide, single pass): T3 = (acc*d + b2) * d -> fp16 table.
__global__ __launch_bounds__(256) void gather8_t3_kernel(
    const int2* __restrict__ rows, const int* __restrict__ col,
    const float* __restrict__ dis, const __half* __restrict__ xin,
    const float* __restrict__ b2, __half* __restrict__ xout, int N) {
    int tid = blockIdx.x * blockDim.x + threadIdx.x;
    int i = tid >> 1;
    int p = tid & 1;
    if (i >= N) return;
    int2 r = rows[i];
    float2 acc[4];
    gather_acc_rng<8, 4, 4>(i, p, r.x, r.y, true, col, (const __half2*)xin, acc);
    float d = dis[i];
    __half2* x2o = (__half2*)xout;
#pragma unroll
    for (int k = 0; k < 4; k++) {
        if ((k >> 1) == p) {
            x2o[(size_t)i * 4 + k] =
                __floats2half2_rn((acc[k].x * d + b2[2 * k]) * d,
                                  (acc[k].y * d + b2[2 * k + 1]) * d);
        }
    }
}

// Layer-3 gather (8-wide, single pass) with fused epilogue:
//   A3 = acc*d; h = relu(A3@W3 + b3) (16); T4 = (h@W4)*d split A(8)/B(4).
// Lane p computes hidden slice [8p,8p+8), partial 12-outputs, shfl-combine;
// lane 0 writes T4a (4 half2), lane 1 writes T4b (2 half2).
__global__ __launch_bounds__(256) void gather8_t4_kernel(
    const int2* __restrict__ rows, const int* __restrict__ col,
    const float* __restrict__ dis, const __half* __restrict__ xin,
    const float* __restrict__ b3, const float* __restrict__ W3,
    const float* __restrict__ W4, __half* __restrict__ xoutA,
    __half* __restrict__ xoutB, int N) {
    __shared__ float sW3[8 * 16];
    __shared__ float sW4[16 * 12];
    __shared__ float sB[16];
    if (threadIdx.x < 128) sW3[threadIdx.x] = W3[threadIdx.x];
    if (threadIdx.x < 192) sW4[threadIdx.x] = W4[threadIdx.x];
    if (threadIdx.x < 16) sB[threadIdx.x] = b3[threadIdx.x];
    __syncthreads();
    int tid = blockIdx.x * blockDim.x + threadIdx.x;
    int i = tid >> 1;
    int p = tid & 1;
    if (i >= N) return;
    int2 r = rows[i];
    float2 acc[4];
    gather_acc_rng<8, 4, 4>(i, p, r.x, r.y, true, col, (const __half2*)xin, acc);
    float d = dis[i];
    float A[8];
#pragma unroll
    for (int k = 0; k < 4; k++) {
        A[2 * k] = acc[k].x * d;
        A[2 * k + 1] = acc[k].y * d;
    }
    float h[8];
#pragma unroll
    for (int f = 0; f < 8; f++) {
        float a = sB[p * 8 + f];
#pragma unroll
        for (int k = 0; k < 8; k++) a = fmaf(A[k], sW3[k * 16 + p * 8 + f], a);
        h[f] = fmaxf(a, 0.0f);
    }
    float o[12];
#pragma unroll
    for (int j = 0; j < 12; j++) {
        float a = 0.0f;
#pragma unroll
        for (int f = 0; f < 8; f++) a = fmaf(h[f], sW4[(p * 8 + f) * 12 + j], a);
        o[j] = a;
    }
#pragma unroll
    for (int j = 0; j < 12; j++) o[j] += __shfl_xor(o[j], 1);
    if (p == 0) {
        __half2* x2a = (__half2*)xoutA;
#pragma unroll
        for (int k = 0; k < 4; k++) {
            x2a[(size_t)i * 4 + k] =
                __floats2half2_rn(o[2 * k] * d, o[2 * k + 1] * d);
        }
    } else {
        __half2* x2b = (__half2*)xoutB;
#pragma unroll
        for (int k = 0; k < 2; k++) {
            x2b[(size_t)i * 2 + k] =
                __floats2half2_rn(o[8 + 2 * k] * d, o[9 + 2 * k] * d);
        }
    }
}

// Layer-4 tail: out = sigmoid((part0+part1)*d + b4), 12-wide.
__global__ __launch_bounds__(256) void combine_sig_kernel(
    const float* __restrict__ p0, const float* __restrict__ p1,
    const float* __restrict__ dis, const float* __restrict__ bias,
    float* __restrict__ out, int N) {
    __shared__ float sB[12];
    if (threadIdx.x < 12) sB[threadIdx.x] = bias[threadIdx.x];
    __syncthreads();
    int i = blockIdx.x * blockDim.x + threadIdx.x;
    if (i >= N) return;
    float d = dis[i];
    const float4* a4 = (const float4*)(p0 + (size_t)i * 12);
    const float4* b4 = (const float4*)(p1 + (size_t)i * 12);
    float4* o4 = (float4*)(out + (size_t)i * 12);
#pragma unroll
    for (int q = 0; q < 3; q++) {
        float4 va = a4[q], vb = b4[q];
        float4 r;
        r.x = 1.0f / (1.0f + expf(-((va.x + vb.x) * d + sB[4 * q + 0])));
        r.y = 1.0f / (1.0f + expf(-((va.y + vb.y) * d + sB[4 * q + 1])));
        r.z = 1.0f / (1.0f + expf(-((va.z + vb.z) * d + sB[4 * q + 2])));
        r.w = 1.0f / (1.0f + expf(-((va.w + vb.w) * d + sB[4 * q + 3])));
        o4[q] = r;
    }
}

static inline size_t align_up(size_t v, size_t a) { return (v + a - 1) & ~(a - 1); }

extern "C" void kernel_launch(void* const* d_in, const int* in_sizes, int n_in,
                              void* d_out, int out_size, void* d_ws, size_t ws_size,
                              hipStream_t stream) {
    const float* x  = (const float*)d_in[0];
    const int*   ei = (const int*)d_in[1];
    const float* W1 = (const float*)d_in[2];
    const float* b1 = (const float*)d_in[3];
    const float* W2 = (const float*)d_in[4];
    const float* b2 = (const float*)d_in[5];
    const float* W3 = (const float*)d_in[6];
    const float* b3 = (const float*)d_in[7];
    const float* W4 = (const float*)d_in[8];
    const float* b4 = (const float*)d_in[9];
    float* out = (float*)d_out;

    const int N = in_sizes[0] / 12;
    const int E = in_sizes[1] / 2;
    const int halfN = N >> 1;
    const int* src = ei;       // edge_index[0]
    const int* dst = ei + E;   // edge_index[1]
    const int NB = (N + NPB - 1) / NPB;  // 391

    // Workspace carve-up (~58 MB); partials alias the dead binned[] region.
    char* ws = (char*)d_ws;
    size_t off = 0;
    int* bucket_cur = (int*)(ws + off);   off = align_up(off + (size_t)NB * 4, 256);
    int2* rows = (int2*)(ws + off);       off = align_up(off + (size_t)N * 8, 256);
    int* mids = (int*)(ws + off);         off = align_up(off + (size_t)N * 4, 256);
    float* dis = (float*)(ws + off);      off = align_up(off + (size_t)N * 4, 256);
    unsigned int* binned = (unsigned int*)(ws + off);
    off = align_up(off + ((size_t)NB * CAP + 4096) * 4, 256);
    int* col = (int*)(ws + off);          off = align_up(off + ((size_t)NB * CAP + 4096) * 4, 256);
    __half* xls = (__half*)(ws + off);    off = align_up(off + (size_t)N * 16 * 2, 256);
    __half* xls2 = (__half*)(ws + off);   off = align_up(off + (size_t)N * 16 * 2, 256);
    (void)ws_size; (void)n_in; (void)out_size;

    // Split-table bases (half units): A = 8 feats (N*8), B = 4 feats (N*4).
    __half* t1a = xls;
    __half* t1b = xls + (size_t)N * 8;
    __half* t2  = xls2;                    // 8-wide T2
    __half* t3  = xls;                     // 8-wide T3 (T1 dead after L1)
    __half* t4a = xls2;                    // T4a (T2 dead after L2 gather)
    __half* t4b = xls2 + (size_t)N * 8;

    // Partials (2 x N x 12 fp32 = 19.2 MB) alias binned (21.1 MB): binned is
    // dead after csr_bucket_t1_kernel completes (stream-ordered).
    float* part0 = (float*)binned;
    float* part1 = part0 + (size_t)N * 12;

    const int B = 256;
    auto blocks = [&](long long n) { return (int)((n + B - 1) / B); };
    int nb2 = blocks(2LL * N);          // ranges for merged gather
    nb2 = (nb2 + 3) & ~3;               // multiple of 4
    const int G2 = nb2 * 2;             // merged-gather grid (mult of 8)

    // --- CSR build (src-half partitioned rows) + fused T1 (split A/B) ----
    init_cur_kernel<<<2, 256, 0, stream>>>(bucket_cur, NB);
    bin_kernel<<<(E + BIN_CHUNK - 1) / BIN_CHUNK, BIN_TH, 0, stream>>>(src, dst, bucket_cur, binned, E, NB);
    csr_bucket_t1_kernel<<<NB, 512, 0, stream>>>(binned, bucket_cur, rows, mids, dis,
                                                 col, x, t1a, t1b, N, halfN);

    // --- Layer 1: single-visit src-half gather (12-wide split) -----------
    gather12h_kernel<<<G2, B, 0, stream>>>(rows, mids, col, t1a, t1b,
                                           part0, part1, N, halfN);

    // --- Layer-1 tail: relu(((p0+p1)*d)@W1+b1)@W2*dis -> T2 (xls2) -------
    transform12_kernel<<<blocks(N), B, 0, stream>>>(part0, part1, b1, W1, W2, dis, t2, N);

    // --- Layer 2: single-pass 8-wide gather -> T3 (xls) ------------------
    gather8_t3_kernel<<<blocks(2LL * N), B, 0, stream>>>(rows, col, dis, t2, b2, t3, N);

    // --- Layer 3: single-pass 8-wide gather + fused W3/relu/W4 -> T4a/b --
    gather8_t4_kernel<<<blocks(2LL * N), B, 0, stream>>>(rows, col, dis, t3, b3, W3, W4,
                                                         t4a, t4b, N);

    // --- Layer 4: single-visit src-half gather (12-wide split) -----------
    gather12h_kernel<<<G2, B, 0, stream>>>(rows, mids, col, t4a, t4b,
                                           part0, part1, N, halfN);

    // --- Layer-4 tail: sigmoid((p0+p1)*d + b4) -> out --------------------
    combine_sig_kernel<<<blocks(N), B, 0, stream>>>(part0, part1, dis, b4, out, N);
}